// Round 13
// baseline (190.221 us; speedup 1.0000x reference)
//
#include <hip/hip_runtime.h>

// Shapes
#define NB   256      // batch
#define E0   300      // embedding
#define EP   304      // padded embedding
#define F_   512      // features
#define KP   1536     // padded K (5*304=1520 -> 48 ksubs of 32 / 12 ss of 128)
#define NKT  48
#define LQ_  64
#define LA_  256

typedef __attribute__((ext_vector_type(4))) float f32x4;
typedef __attribute__((ext_vector_type(8))) short short8;

#define XQ_ELEMS (NB * (LQ_ + 4) * EP)   // 5,292,032
#define XA_ELEMS (NB * (LA_ + 4) * EP)   // 20,234,240
#define WF_ELEMS (F_ * KP)               // 786,432 (16f-fragment-packed)
#define OUTQ_ELEMS ((size_t)NB * F_ * LQ_)
#define XROWS (NB * (LQ_ + 4) + NB * (LA_ + 4))   // 83,968

__device__ __forceinline__ unsigned short f2bf(float x) {
    unsigned int u = __float_as_uint(x);
    u = u + 0x7fffu + ((u >> 16) & 1u);   // RNE
    return (unsigned short)(u >> 16);
}

// Zero-padded bf16 x with halo, flat-indexed dense blocks. (Verified r6-r12.)
__global__ void prep_x(const float* __restrict__ q, const float* __restrict__ a,
                       unsigned short* __restrict__ xq, unsigned short* __restrict__ xa)
{
    int idx = blockIdx.x * 256 + threadIdx.x;
    if (idx >= XROWS * 76) return;
    int row = idx / 76;
    int col = idx - row * 76;

    const float* src;
    unsigned short* dst;
    bool valid;
    if (row < NB * (LQ_ + 4)) {
        int b = row / (LQ_ + 4), lp = row - b * (LQ_ + 4);
        dst = xq + (size_t)row * EP;
        valid = (lp >= 2 && lp < 2 + LQ_);
        src = q + ((size_t)b * LQ_ + (lp - 2)) * E0;
    } else {
        int r2 = row - NB * (LQ_ + 4);
        int b = r2 / (LA_ + 4), lp = r2 - b * (LA_ + 4);
        dst = xa + (size_t)r2 * EP;
        valid = (lp >= 2 && lp < 2 + LA_);
        src = a + ((size_t)b * LA_ + (lp - 2)) * E0;
    }
    unsigned long long pk = 0ull;
    if (valid && col < 75) {
        const float4 v = reinterpret_cast<const float4*>(src)[col];
        pk = (unsigned long long)f2bf(v.x)
           | ((unsigned long long)f2bf(v.y) << 16)
           | ((unsigned long long)f2bf(v.z) << 32)
           | ((unsigned long long)f2bf(v.w) << 48);
    }
    *reinterpret_cast<unsigned long long*>(dst + (size_t)col * 4) = pk;
}

// Fragment-packed W (verified r5-r9): chunk (tile16, kc) = 1024B, lane holds
// f = tile16*16 + (lane&15), k' = kc*32 + (lane>>4)*8 + j.
__global__ void prep_w2(const float* __restrict__ W, unsigned short* __restrict__ wfr)
{
    int idx = blockIdx.x * 256 + threadIdx.x;
    int j    = idx & 7;
    int lane = (idx >> 3) & 63;
    int chunk = idx >> 9;
    int kc = chunk % NKT;
    int tile16 = chunk / NKT;
    int f  = tile16 * 16 + (lane & 15);
    int kp = kc * 32 + (lane >> 4) * 8 + j;
    int jj = kp / EP;
    int e  = kp - jj * EP;
    float v = (kp < 5 * EP && e < E0) ? W[(size_t)(jj * E0 + e) * F_ + f] : 0.f;
    wfr[idx] = f2bf(v);
}

// r13: 256f x 128l tile, 4 waves (wave = 64f x 128l, acc[4][8], 32 mfma/fence).
// Ring-2 LDS 64 KB (2 bufs x 4 ksubs x [128][32]).  2 blocks/CU.
// Persistent grid 512: block wg does tiles {wg, wg+512, wg+1024<1280}; all
// tiles of a block share ftBase (same W stream).  Every CU gets 5 tiles.
// Per-wave in-order VMEM ledger (W4 = 4 loads, ST8 = 8 GLLDS):
//   tile prologue: W4(k0); ST8(ss0) -> vmcnt(0), barrier (drains epi stores too).
//   SS S: issue ST8(S+1) (S<11), ZRD8(ks0 of cur buf);
//     ks0: fence vmcnt(8) lgkm(0)  [entering outstanding = W4(prev ks3) + ST8 ->
//          retires W4p];  32 mfma in 2 halves; ZRD4x2 -> ks1; W4.
//     ks1: fence vmcnt(0) [retires ST8(S+1) + W4(ks0)]; ...; W4.
//     ks2/ks3: vmcnt(0); ks3 has no ZRD (no cross-SS prefetch -> no race);
//     s_barrier ends the SS (publishes ST8(S+1) CU-wide: every wave passed its
//     own ks1 fence which retired its ST8).
//   WAR: ST8(S+1) -> buf (S+1)&1, last read in SS S-1 (reads lgkm-drained at
//   its ks3 fence, before the end-of-(S-1) barrier, after which ST8 issues).
//   S=11: no ST8; ks0 fence vmcnt(0); ks3 no W4 (chain ends at k47).
__global__ __launch_bounds__(256, 2) void qa_gemm(
    const unsigned short* __restrict__ xq,
    const unsigned short* __restrict__ xa,
    const unsigned short* __restrict__ wfr,
    const float* __restrict__ bias,
    float* __restrict__ out)
{
    __shared__ __align__(16) unsigned short lds[2 * 16384];   // 64 KB Z-ring

    const int bid = blockIdx.x;
    const int wg  = (bid & 7) * 64 + (bid >> 3);   // XCD swizzle, 512 % 8 == 0

    const int ftBase = (wg & 1) * 256;             // constant per block
    const int ltBase = wg >> 1;                    // 0..255
    const int ntile  = (wg < 256) ? 3 : 2;         // 1280 tiles total

    const int tid  = threadIdx.x;
    const int lane = tid & 63;
    const int wid  = tid >> 6;      // wave = 64f slice; all share the 128l tile
    const int lq   = lane >> 4;
    const int lr   = lane & 15;
    const int s_c  = (lane & 3) ^ ((lane >> 3) & 3);
    const int sub  = lane >> 2;
    const int dzA  = wid * 1024;    // shorts: stage rows wid*32..+15
    const int dzB  = dzA + 512;     //          and +16..+31

    // ---- W fragment chain bases (verified r5-r9 layout)
    const unsigned short* wb0 = wfr + (size_t)((ftBase >> 4) + wid * 4 + 0) * NKT * 512 + lane * 8;
    const unsigned short* wb1 = wfr + (size_t)((ftBase >> 4) + wid * 4 + 1) * NKT * 512 + lane * 8;
    const unsigned short* wb2 = wfr + (size_t)((ftBase >> 4) + wid * 4 + 2) * NKT * 512 + lane * 8;
    const unsigned short* wb3 = wfr + (size_t)((ftBase >> 4) + wid * 4 + 3) * NKT * 512 + lane * 8;

    // ---- Z fragment LDS offsets (bytes within a ksub block; r8-verified family)
    const int cs = (lq ^ ((lr >> 1) & 3)) * 16;
    int zoff[8];
#pragma unroll
    for (int n = 0; n < 8; ++n) zoff[n] = (n * 16 + lr) * 64 + cs;

#define GLLDS(p, d) __builtin_amdgcn_global_load_lds(                               \
        (const __attribute__((address_space(1))) void*)(p),                         \
        (__attribute__((address_space(3))) void*)(d), 16, 0, 0)
#define ST8(T) do { const int rb = ((T) & 1) * 16384; const size_t ko = (size_t)(T) * 128; \
    _Pragma("unroll") for (int kb = 0; kb < 4; ++kb) {                              \
        GLLDS(gZ0 + ko + kb * 32, lds + rb + kb * 4096 + dzA);                      \
        GLLDS(gZ1 + ko + kb * 32, lds + rb + kb * 4096 + dzB); } } while (0)
#define WLOAD(dst, p) do {                                                           \
    asm volatile("global_load_dwordx4 %0, %1, off" : "=v"(dst) : "v"(p) : "memory"); \
    (p) += 512; } while (0)
#define W4(SET) do { WLOAD(SET[0], wp0); WLOAD(SET[1], wp1);                         \
                     WLOAD(SET[2], wp2); WLOAD(SET[3], wp3); } while (0)
#define ZRD4(H, KB) do { _Pragma("unroll") for (int n = 0; n < 4; ++n)               \
    zc[(H) * 4 + n] = *(const short8*)(bbase + (KB) * 8192 + zoff[(H) * 4 + n]); } while (0)
#define MFMA16(H, WU) do { _Pragma("unroll") for (int mf = 0; mf < 4; ++mf)          \
    _Pragma("unroll") for (int n = 0; n < 4; ++n)                                    \
        acc[mf][(H) * 4 + n] = __builtin_amdgcn_mfma_f32_16x16x32_bf16(              \
            WU[mf], zc[(H) * 4 + n], acc[mf][(H) * 4 + n], 0, 0, 0); } while (0)
#define SB __builtin_amdgcn_sched_barrier(0)
// One ksub: fence -> 16 mfma -> refill zc[0..3] -> 16 mfma -> refill zc[4..7] -> W4
#define KSUB(KBN, WU, WL, DO_Z, DO_W, VM) do {                                       \
    asm volatile("s_waitcnt vmcnt(" #VM ") lgkmcnt(0)" ::: "memory"); SB;            \
    __builtin_amdgcn_s_setprio(1); MFMA16(0, WU); __builtin_amdgcn_s_setprio(0); SB; \
    if (DO_Z) { ZRD4(0, KBN); }                                                      \
    __builtin_amdgcn_s_setprio(1); MFMA16(1, WU); __builtin_amdgcn_s_setprio(0); SB; \
    if (DO_Z) { ZRD4(1, KBN); }                                                      \
    if (DO_W) { W4(WL); }                                                            \
} while (0)

    for (int ti = 0; ti < ntile; ++ti) {
        const int lt = ltBase + ti * 256;          // l-tile of 128 rows
        const unsigned short* xp;
        float* ob;
        int Mb, lsh, Lp;
        if (lt < 128) { Mb = lt * 128;         xp = xq; lsh = 6; Lp = LQ_ + 4; ob = out; }
        else          { Mb = (lt - 128) * 128; xp = xa; lsh = 8; Lp = LA_ + 4; ob = out + OUTQ_ELEMS; }
        const int Lv = 1 << lsh;

        const int mr0 = Mb + wid * 32 + sub;
        const int mr1 = mr0 + 16;
        const unsigned short* gZ0 = xp + (size_t)((mr0 >> lsh) * Lp + (mr0 & (Lv - 1))) * EP + s_c * 8;
        const unsigned short* gZ1 = xp + (size_t)((mr1 >> lsh) * Lp + (mr1 & (Lv - 1))) * EP + s_c * 8;

        const unsigned short* wp0 = wb0;
        const unsigned short* wp1 = wb1;
        const unsigned short* wp2 = wb2;
        const unsigned short* wp3 = wb3;

        f32x4 acc[4][8] = {};                      // [mf][nt]
        short8 zc[8], wA[4], wB[4];

        // Tile prologue (vmcnt(0) also drains the previous tile's stores)
        W4(wA);
        ST8(0);
        asm volatile("s_waitcnt vmcnt(0)\n\ts_barrier" ::: "memory");

        for (int S = 0; S < 11; ++S) {
            if (S < 11) ST8(S + 1);
            const char* bbase = (const char*)lds + (S & 1) * 32768;
            ZRD4(0, 0); ZRD4(1, 0);
            KSUB(1, wA, wB, 1, 1, 8);              // ks0 (retires W4p)
            KSUB(2, wB, wA, 1, 1, 0);              // ks1 (forces ST8(S+1))
            KSUB(3, wA, wB, 1, 1, 0);              // ks2
            KSUB(0, wB, wA, 0, 1, 0);              // ks3 (loads next-SS k0)
            asm volatile("s_barrier" ::: "memory");
        }
        {   // S = 11: no ST8; W chain ends at k47
            const char* bbase = (const char*)lds + 32768;
            ZRD4(0, 0); ZRD4(1, 0);
            KSUB(1, wA, wB, 1, 1, 0);
            KSUB(2, wB, wA, 1, 1, 0);
            KSUB(3, wA, wB, 1, 1, 0);
            KSUB(0, wB, wA, 0, 0, 0);
            asm volatile("s_barrier" ::: "memory");
        }

        // ---- epilogue: D row = f = lq*4+reg, col = l = lr (verified r1-r12)
#pragma unroll
        for (int nt = 0; nt < 8; ++nt) {
            const int m = Mb + nt * 16 + lr;
            const int b = m >> lsh;
            const int l = m & (Lv - 1);
            float* orow = ob + ((size_t)b * F_ << lsh) + l;
#pragma unroll
            for (int mf = 0; mf < 4; ++mf) {
                const int f0 = ftBase + wid * 64 + mf * 16 + lq * 4;
                const f32x4 v = acc[mf][nt];
#pragma unroll
                for (int r = 0; r < 4; ++r)
                    orow[(size_t)(f0 + r) << lsh] = v[r] + __ldg(&bias[f0 + r]);
            }
        }
    }

#undef KSUB
#undef SB
#undef MFMA16
#undef ZRD4
#undef W4
#undef WLOAD
#undef ST8
#undef GLLDS
}

extern "C" void kernel_launch(void* const* d_in, const int* in_sizes, int n_in,
                              void* d_out, int out_size, void* d_ws, size_t ws_size,
                              hipStream_t stream)
{
    const float* q    = (const float*)d_in[0];
    const float* a    = (const float*)d_in[1];
    const float* W    = (const float*)d_in[2];
    const float* bias = (const float*)d_in[3];
    float* out = (float*)d_out;

    unsigned short* xq  = (unsigned short*)d_ws;
    unsigned short* xa  = xq + XQ_ELEMS;
    unsigned short* wfr = xa + XA_ELEMS;
    // ws needed: (XQ+XA+WF)*2 = 52.6 MB.  xa K-pad tail reads overrun <=32 B
    // into wfr: in-bounds; the matching W fragments are zero -> don't-care.

    prep_x<<<(XROWS * 76 + 255) / 256, 256, 0, stream>>>(q, a, xq, xa);
    prep_w2<<<WF_ELEMS / 256, 256, 0, stream>>>(W, wfr);
    qa_gemm<<<512, 256, 0, stream>>>(xq, xa, wfr, bias, out);
}

// Round 14
// 151.969 us; speedup vs baseline: 1.2517x; 1.2517x over previous
//
#include <hip/hip_runtime.h>

// Shapes
#define NB   256      // batch
#define E0   300      // embedding
#define EP   304      // padded embedding
#define F_   512      // features
#define KP   1536     // padded K (5*304=1520 -> 48 ksubs of 32 / 12 ss of 128)
#define NKT  48
#define LQ_  64
#define LA_  256

typedef __attribute__((ext_vector_type(4))) float f32x4;
typedef __attribute__((ext_vector_type(8))) short short8;

#define XQ_ELEMS (NB * (LQ_ + 4) * EP)   // 5,292,032
#define XA_ELEMS (NB * (LA_ + 4) * EP)   // 20,234,240
#define WF_ELEMS (F_ * KP)               // 786,432 (16f-fragment-packed)
#define OUTQ_ELEMS ((size_t)NB * F_ * LQ_)
#define XROWS (NB * (LQ_ + 4) + NB * (LA_ + 4))   // 83,968

__device__ __forceinline__ unsigned short f2bf(float x) {
    unsigned int u = __float_as_uint(x);
    u = u + 0x7fffu + ((u >> 16) & 1u);   // RNE
    return (unsigned short)(u >> 16);
}

// Zero-padded bf16 x with halo, flat-indexed dense blocks. (Verified r6-r13.)
__global__ void prep_x(const float* __restrict__ q, const float* __restrict__ a,
                       unsigned short* __restrict__ xq, unsigned short* __restrict__ xa)
{
    int idx = blockIdx.x * 256 + threadIdx.x;
    if (idx >= XROWS * 76) return;
    int row = idx / 76;
    int col = idx - row * 76;

    const float* src;
    unsigned short* dst;
    bool valid;
    if (row < NB * (LQ_ + 4)) {
        int b = row / (LQ_ + 4), lp = row - b * (LQ_ + 4);
        dst = xq + (size_t)row * EP;
        valid = (lp >= 2 && lp < 2 + LQ_);
        src = q + ((size_t)b * LQ_ + (lp - 2)) * E0;
    } else {
        int r2 = row - NB * (LQ_ + 4);
        int b = r2 / (LA_ + 4), lp = r2 - b * (LA_ + 4);
        dst = xa + (size_t)r2 * EP;
        valid = (lp >= 2 && lp < 2 + LA_);
        src = a + ((size_t)b * LA_ + (lp - 2)) * E0;
    }
    unsigned long long pk = 0ull;
    if (valid && col < 75) {
        const float4 v = reinterpret_cast<const float4*>(src)[col];
        pk = (unsigned long long)f2bf(v.x)
           | ((unsigned long long)f2bf(v.y) << 16)
           | ((unsigned long long)f2bf(v.z) << 32)
           | ((unsigned long long)f2bf(v.w) << 48);
    }
    *reinterpret_cast<unsigned long long*>(dst + (size_t)col * 4) = pk;
}

// Fragment-packed W (verified r5-r13): chunk (tile16, kc) = 1024B, lane holds
// f = tile16*16 + (lane&15), k' = kc*32 + (lane>>4)*8 + j.
__global__ void prep_w2(const float* __restrict__ W, unsigned short* __restrict__ wfr)
{
    int idx = blockIdx.x * 256 + threadIdx.x;
    int j    = idx & 7;
    int lane = (idx >> 3) & 63;
    int chunk = idx >> 9;
    int kc = chunk % NKT;
    int tile16 = chunk / NKT;
    int f  = tile16 * 16 + (lane & 15);
    int kp = kc * 32 + (lane >> 4) * 8 + j;
    int jj = kp / EP;
    int e  = kp - jj * EP;
    float v = (kp < 5 * EP && e < E0) ? W[(size_t)(jj * E0 + e) * F_ + f] : 0.f;
    wfr[idx] = f2bf(v);
}

// r14: 256f x 128l tile, 4 waves (wave = 64f x 128l, acc[4][8], 32 mfma/fence),
// ring-2 LDS 64 KB, 2 blocks/CU, grid 1280 (1 tile/block, HW backfill).
// W: 2 sets wA (even ksubs) / wB (odd), each reloaded 2-ksubs-ahead AFTER its
//    MFMA use.  Z: ST8(S+1) at SS start; reg dbuf zA/zB, no cross-SS ZRD.
// Per-wave in-order VM ledger (W4 = 4 loads, ST8 = 8 loads):
//   Steady entry to SS S: queue = [W4@ks2(S-1) (wA for ks0), W4@ks3(S-1) (wB
//   for ks1)].  SS start: +ST8(S+1).
//   fence@ks0 vmcnt(12): retires W4@ks2(S-1)  -> wA(ks0) ready.
//   fence@ks1 vmcnt(12): retires W4@ks3(S-1)  -> wB(ks1) ready.
//   fence@ks2 vmcnt(4):  retires W4@ks0 (wA for ks2) AND ST8(S+1) (~3-ksub
//                        window; publication before the end-of-S barrier).
//   fence@ks3 vmcnt(4):  retires W4@ks1 (wB for ks3).
//   lgkm(8) at ks0-ks2 (current blk's 8 ds_reads done, next's 8 in flight);
//   lgkm(0) at ks3 (drains blk3 reads -> WAR-safe for next-next ST8).
//   Prologue: W4A(k0), W4B(k1), ST8(ss0) -> vmcnt(0), barrier.
//   SS11 (no ST8): fences 4,4,4,0; W4 only at ks0 (k46), ks1 (k47).
__global__ __launch_bounds__(256, 2) void qa_gemm(
    const unsigned short* __restrict__ xq,
    const unsigned short* __restrict__ xa,
    const unsigned short* __restrict__ wfr,
    const float* __restrict__ bias,
    float* __restrict__ out)
{
    __shared__ __align__(16) unsigned short lds[2 * 16384];   // 64 KB Z-ring

    const int bid = blockIdx.x;
    const int wg  = (bid & 7) * 160 + (bid >> 3);   // XCD swizzle, 1280 % 8 == 0

    const int ftBase = (wg & 1) * 256;
    const int lt     = wg >> 1;                     // 0..639, tile of 128 l-rows

    const unsigned short* xp;
    float* ob;
    int Mb, lsh, Lp;
    if (lt < 128) { Mb = lt * 128;         xp = xq; lsh = 6; Lp = LQ_ + 4; ob = out; }
    else          { Mb = (lt - 128) * 128; xp = xa; lsh = 8; Lp = LA_ + 4; ob = out + OUTQ_ELEMS; }
    const int Lv = 1 << lsh;

    const int tid  = threadIdx.x;
    const int lane = tid & 63;
    const int wid  = tid >> 6;      // wave = 64f slice; all share the 128l tile
    const int lq   = lane >> 4;
    const int lr   = lane & 15;
    const int s_c  = (lane & 3) ^ ((lane >> 3) & 3);
    const int sub  = lane >> 2;
    const int dzA  = wid * 1024;    // shorts: stage rows wid*32..+15
    const int dzB  = dzA + 512;     //          and +16..+31

    const int mr0 = Mb + wid * 32 + sub;
    const int mr1 = mr0 + 16;
    const unsigned short* gZ0 = xp + (size_t)((mr0 >> lsh) * Lp + (mr0 & (Lv - 1))) * EP + s_c * 8;
    const unsigned short* gZ1 = xp + (size_t)((mr1 >> lsh) * Lp + (mr1 & (Lv - 1))) * EP + s_c * 8;

    // ---- W fragment chains (verified layout); two sets, stride 2 kc per load
    const unsigned short* wpA0 = wfr + (size_t)((ftBase >> 4) + wid * 4 + 0) * NKT * 512 + lane * 8;
    const unsigned short* wpA1 = wfr + (size_t)((ftBase >> 4) + wid * 4 + 1) * NKT * 512 + lane * 8;
    const unsigned short* wpA2 = wfr + (size_t)((ftBase >> 4) + wid * 4 + 2) * NKT * 512 + lane * 8;
    const unsigned short* wpA3 = wfr + (size_t)((ftBase >> 4) + wid * 4 + 3) * NKT * 512 + lane * 8;
    const unsigned short* wpB0 = wpA0 + 512;
    const unsigned short* wpB1 = wpA1 + 512;
    const unsigned short* wpB2 = wpA2 + 512;
    const unsigned short* wpB3 = wpA3 + 512;

    // ---- Z fragment LDS offsets (bytes within a ksub blk; r8-verified family)
    const int cs = (lq ^ ((lr >> 1) & 3)) * 16;
    int zoff[8];
#pragma unroll
    for (int n = 0; n < 8; ++n) zoff[n] = (n * 16 + lr) * 64 + cs;

#define GLLDS(p, d) __builtin_amdgcn_global_load_lds(                               \
        (const __attribute__((address_space(1))) void*)(p),                         \
        (__attribute__((address_space(3))) void*)(d), 16, 0, 0)
#define ST8(T) do { const int rb = ((T) & 1) * 16384; const size_t ko = (size_t)(T) * 128; \
    _Pragma("unroll") for (int kb = 0; kb < 4; ++kb) {                              \
        GLLDS(gZ0 + ko + kb * 32, lds + rb + kb * 4096 + dzA);                      \
        GLLDS(gZ1 + ko + kb * 32, lds + rb + kb * 4096 + dzB); } } while (0)
#define WLOAD(dst, p) do {                                                           \
    asm volatile("global_load_dwordx4 %0, %1, off" : "=v"(dst) : "v"(p) : "memory"); \
    (p) += 1024; } while (0)
#define W4A do { WLOAD(wA[0], wpA0); WLOAD(wA[1], wpA1);                             \
                 WLOAD(wA[2], wpA2); WLOAD(wA[3], wpA3); } while (0)
#define W4B do { WLOAD(wB[0], wpB0); WLOAD(wB[1], wpB1);                             \
                 WLOAD(wB[2], wpB2); WLOAD(wB[3], wpB3); } while (0)
#define ZRD8(DST, BLK) do { _Pragma("unroll") for (int n = 0; n < 8; ++n)            \
    DST[n] = *(const short8*)(bbase + (BLK) * 8192 + zoff[n]); } while (0)
#define SB __builtin_amdgcn_sched_barrier(0)
#define FENCE(VM, LG) do {                                                           \
    asm volatile("s_waitcnt vmcnt(" #VM ") lgkmcnt(" #LG ")" ::: "memory"); SB; } while (0)
#define MFMA32K(WU, ZU) do { __builtin_amdgcn_s_setprio(1);                          \
    _Pragma("unroll") for (int mf = 0; mf < 4; ++mf)                                 \
    _Pragma("unroll") for (int nt = 0; nt < 8; ++nt)                                 \
        acc[mf][nt] = __builtin_amdgcn_mfma_f32_16x16x32_bf16(                       \
            WU[mf], ZU[nt], acc[mf][nt], 0, 0, 0);                                   \
    __builtin_amdgcn_s_setprio(0); SB; } while (0)

    f32x4 acc[4][8] = {};
    short8 zA[8], zB[8], wA[4], wB[4];

    // Prologue: wA(k0), wB(k1), stage ss0; drain; publish.
    W4A; W4B;
    ST8(0);
    asm volatile("s_waitcnt vmcnt(0)\n\ts_barrier" ::: "memory");

    for (int S = 0; S < 11; ++S) {
        ST8(S + 1);
        const char* bbase = (const char*)lds + (S & 1) * 32768;
        ZRD8(zA, 0);
        /* ks0 */ ZRD8(zB, 1); FENCE(12, 8); MFMA32K(wA, zA); W4A;
        /* ks1 */ ZRD8(zA, 2); FENCE(12, 8); MFMA32K(wB, zB); W4B;
        /* ks2 */ ZRD8(zB, 3); FENCE(4,  8); MFMA32K(wA, zA); W4A;
        /* ks3 */              FENCE(4,  0); MFMA32K(wB, zB); W4B;
        asm volatile("s_barrier" ::: "memory");
    }
    {   // SS 11: no stage; W4 only at ks0 (k46) and ks1 (k47)
        const char* bbase = (const char*)lds + 32768;
        ZRD8(zA, 0);
        /* ks0 */ ZRD8(zB, 1); FENCE(4, 8); MFMA32K(wA, zA); W4A;
        /* ks1 */ ZRD8(zA, 2); FENCE(4, 8); MFMA32K(wB, zB); W4B;
        /* ks2 */ ZRD8(zB, 3); FENCE(4, 8); MFMA32K(wA, zA);
        /* ks3 */              FENCE(0, 0); MFMA32K(wB, zB);
    }

#undef MFMA32K
#undef FENCE
#undef SB
#undef ZRD8
#undef W4A
#undef W4B
#undef WLOAD
#undef ST8
#undef GLLDS

    // ---- epilogue: D row = f = lq*4+reg, col = l = lr (verified r1-r13)
#pragma unroll
    for (int nt = 0; nt < 8; ++nt) {
        const int m = Mb + nt * 16 + lr;
        const int b = m >> lsh;
        const int l = m & (Lv - 1);
        float* orow = ob + ((size_t)b * F_ << lsh) + l;
#pragma unroll
        for (int mf = 0; mf < 4; ++mf) {
            const int f0 = ftBase + wid * 64 + mf * 16 + lq * 4;
            const f32x4 v = acc[mf][nt];
#pragma unroll
            for (int r = 0; r < 4; ++r)
                orow[(size_t)(f0 + r) << lsh] = v[r] + __ldg(&bias[f0 + r]);
        }
    }
}

extern "C" void kernel_launch(void* const* d_in, const int* in_sizes, int n_in,
                              void* d_out, int out_size, void* d_ws, size_t ws_size,
                              hipStream_t stream)
{
    const float* q    = (const float*)d_in[0];
    const float* a    = (const float*)d_in[1];
    const float* W    = (const float*)d_in[2];
    const float* bias = (const float*)d_in[3];
    float* out = (float*)d_out;

    unsigned short* xq  = (unsigned short*)d_ws;
    unsigned short* xa  = xq + XQ_ELEMS;
    unsigned short* wfr = xa + XA_ELEMS;
    // ws needed: (XQ+XA+WF)*2 = 52.6 MB.  xa K-pad tail reads overrun <=32 B
    // into wfr: in-bounds; the matching W fragments are zero -> don't-care.

    prep_x<<<(XROWS * 76 + 255) / 256, 256, 0, stream>>>(q, a, xq, xa);
    prep_w2<<<WF_ELEMS / 256, 256, 0, stream>>>(W, wfr);
    qa_gemm<<<1280, 256, 0, stream>>>(xq, xa, wfr, bias, out);
}